// Round 3
// baseline (369.317 us; speedup 1.0000x reference)
//
#include <hip/hip_runtime.h>

#define N_NODES 100000
#define N_EDGES 1600000
#define D 128
#define N_STRIPS (N_NODES / 32)     // 3125

#define E4      (N_EDGES / 4)       // 400000 int4 records
#define HB_BLK  391                 // 391*1024 = 400384 >= E4; block 391 casts W
#define NSCB    98                  // 98*1024 = 100352 >= N_NODES

typedef __bf16 bf16x4 __attribute__((ext_vector_type(4)));
typedef __bf16 bf16x8 __attribute__((ext_vector_type(8)));
typedef float  f32x4  __attribute__((ext_vector_type(4)));

// ---- histogram of in-degree via device-scope atomics (spread over 100K
// addresses -> negligible contention); block HB_BLK casts W -> bf16 ----
__global__ __launch_bounds__(1024) void k_hist(const int4* __restrict__ col4,
                                               const float4* __restrict__ w4,
                                               int* __restrict__ deg,
                                               bf16x4* __restrict__ wb4) {
    int b = blockIdx.x, t = threadIdx.x;
    if (b == HB_BLK) {                     // cast W -> bf16 (4096 float4)
        for (int i = t; i < (D * D) / 4; i += 1024) {
            float4 u = w4[i];
            bf16x4 p;
            p[0] = (__bf16)u.x; p[1] = (__bf16)u.y;
            p[2] = (__bf16)u.z; p[3] = (__bf16)u.w;
            wb4[i] = p;
        }
        return;
    }
    int i = b * 1024 + t;
    if (i < E4) {
        int4 c = col4[i];
        atomicAdd(&deg[c.x], 1);
        atomicAdd(&deg[c.y], 1);
        atomicAdd(&deg[c.z], 1);
        atomicAdd(&deg[c.w], 1);
    }
}

// ---- per-block exclusive scan of deg (1024 elements/block) ----
__global__ __launch_bounds__(1024) void k_scanl(const int* __restrict__ deg,
                                                int* __restrict__ start,
                                                int* __restrict__ btot) {
    __shared__ int buf[1024];
    int b = blockIdx.x, t = threadIdx.x;
    int i = b * 1024 + t;
    int v = (i < N_NODES) ? deg[i] : 0;
    buf[t] = v;
    __syncthreads();
    for (int off = 1; off < 1024; off <<= 1) {
        int u = (t >= off) ? buf[t - off] : 0;
        __syncthreads();
        buf[t] += u;
        __syncthreads();
    }
    if (i < N_NODES) start[i] = buf[t] - v;      // local exclusive
    if (t == 1023) btot[b] = buf[1023];
}

// ---- fixup: add block offsets (prefix of btot computed in-block),
// produce final start, mutable cursor copy, and dis = rsqrt(deg+1) ----
__global__ __launch_bounds__(1024) void k_fixup(const int* __restrict__ deg,
                                                const int* __restrict__ btot,
                                                int* __restrict__ start,
                                                int* __restrict__ cur,
                                                float* __restrict__ dis) {
    __shared__ int red[128];
    int b = blockIdx.x, t = threadIdx.x;
    if (t < 128) red[t] = (t < b) ? btot[t] : 0;   // b <= NSCB-1 < 128
    __syncthreads();
    for (int off = 64; off > 0; off >>= 1) {
        if (t < off) red[t] += red[t + off];
        __syncthreads();
    }
    int boff = red[0];
    int i = b * 1024 + t;
    if (i < N_NODES) {
        int s = start[i] + boff;
        start[i] = s;
        cur[i]   = s;
        dis[i]   = rsqrtf((float)deg[i] + 1.0f);
    }
}

// ---- direct single-pass scatter: srcs[pos] = row << 8 (byte offset into hb) ----
__global__ __launch_bounds__(1024) void k_scatter(const int4* __restrict__ row4,
                                                  const int4* __restrict__ col4,
                                                  int* __restrict__ cur,
                                                  int* __restrict__ srcs) {
    int i = blockIdx.x * 1024 + threadIdx.x;
    if (i >= E4) return;
    int4 r = row4[i];
    int4 c = col4[i];
    int p0 = atomicAdd(&cur[c.x], 1);
    int p1 = atomicAdd(&cur[c.y], 1);
    int p2 = atomicAdd(&cur[c.z], 1);
    int p3 = atomicAdd(&cur[c.w], 1);
    srcs[p0] = r.x << 8;
    srcs[p1] = r.y << 8;
    srcs[p2] = r.z << 8;
    srcs[p3] = r.w << 8;
}

// ---- transform-first: hb[row] = bf16( (x @ W^T)[row] * dis[row] ) via bf16 MFMA ----
__global__ __launch_bounds__(256) void k_hx(const float* __restrict__ x,
                                            const __bf16* __restrict__ wb,
                                            const float* __restrict__ dis,
                                            __bf16* __restrict__ hb) {
    int wave = threadIdx.x >> 6;
    int lane = threadIdx.x & 63;
    int strip = blockIdx.x * 4 + wave;
    if (strip >= N_STRIPS) return;
    int m0 = strip * 32;
    int l15 = lane & 15;
    int kq  = lane >> 4;

    bf16x8 a[2][4];
    #pragma unroll
    for (int mt = 0; mt < 2; ++mt) {
        const float* ap = x + (size_t)(m0 + mt * 16 + l15) * D + kq * 8;
        #pragma unroll
        for (int ks = 0; ks < 4; ++ks) {
            float4 lo = *(const float4*)(ap + ks * 32);
            float4 hi = *(const float4*)(ap + ks * 32 + 4);
            bf16x8 t;
            t[0] = (__bf16)lo.x; t[1] = (__bf16)lo.y;
            t[2] = (__bf16)lo.z; t[3] = (__bf16)lo.w;
            t[4] = (__bf16)hi.x; t[5] = (__bf16)hi.y;
            t[6] = (__bf16)hi.z; t[7] = (__bf16)hi.w;
            a[mt][ks] = t;
        }
    }

    f32x4 acc[2][8] = {};
    #pragma unroll
    for (int ks = 0; ks < 4; ++ks) {
        #pragma unroll
        for (int nt = 0; nt < 8; ++nt) {
            bf16x8 b = *(const bf16x8*)(wb + (size_t)(nt * 16 + l15) * D + ks * 32 + kq * 8);
            acc[0][nt] = __builtin_amdgcn_mfma_f32_16x16x32_bf16(a[0][ks], b, acc[0][nt], 0, 0, 0);
            acc[1][nt] = __builtin_amdgcn_mfma_f32_16x16x32_bf16(a[1][ks], b, acc[1][nt], 0, 0, 0);
        }
    }

    float dsv[2][4];
    #pragma unroll
    for (int mt = 0; mt < 2; ++mt)
        #pragma unroll
        for (int r = 0; r < 4; ++r)
            dsv[mt][r] = dis[m0 + mt * 16 + kq * 4 + r];

    #pragma unroll
    for (int nt = 0; nt < 8; ++nt) {
        int colj = nt * 16 + l15;
        #pragma unroll
        for (int mt = 0; mt < 2; ++mt) {
            #pragma unroll
            for (int r = 0; r < 4; ++r) {
                int rowi = m0 + mt * 16 + kq * 4 + r;
                hb[(size_t)rowi * D + colj] = (__bf16)(acc[mt][nt][r] * dsv[mt][r]);
            }
        }
    }
}

// ---- gather-aggregate: one wave per destination, 32 lanes x 8B per row,
// two source rows per VMEM instruction; srcs hold byte offsets already ----
__global__ __launch_bounds__(256) void k_aggregate(const int* __restrict__ srcs,
                                                   const int* __restrict__ start,
                                                   const int* __restrict__ deg,
                                                   const __bf16* __restrict__ hb,
                                                   const float* __restrict__ dis,
                                                   const float* __restrict__ bias,
                                                   float* __restrict__ out) {
    int node = (blockIdx.x * 256 + threadIdx.x) >> 6;
    int lane = threadIdx.x & 63;
    if (node >= N_NODES) return;
    int li   = lane & 31;          // 8B slot within row (cols 4*li .. 4*li+3)
    int half = lane >> 5;          // which of 2 edges this half-wave handles
    int s = start[node];
    int n = deg[node];
    float dc = dis[node];
    const unsigned char* hbase = (const unsigned char*)hb;
    size_t boff = (size_t)li * 8;

    float acc0 = 0.f, acc1 = 0.f, acc2 = 0.f, acc3 = 0.f;

    for (int base = 0; base < n; base += 64) {
        int m = n - base; if (m > 64) m = 64;
        int src_l = (lane < m) ? srcs[s + base + lane] : 0;   // byte offsets
        int i = 0;
        for (; i + 16 <= m; i += 16) {          // 16 edges per batch (8 per half)
            int sv[8]; uint2 av[8];
            #pragma unroll
            for (int j = 0; j < 8; ++j)
                sv[j] = __shfl(src_l, i + 2 * j + half);
            #pragma unroll
            for (int j = 0; j < 8; ++j)
                av[j] = *(const uint2*)(hbase + ((size_t)sv[j] + boff));
            #pragma unroll
            for (int j = 0; j < 8; ++j) {
                acc0 += __uint_as_float(av[j].x << 16);
                acc1 += __uint_as_float(av[j].x & 0xFFFF0000u);
                acc2 += __uint_as_float(av[j].y << 16);
                acc3 += __uint_as_float(av[j].y & 0xFFFF0000u);
            }
        }
        for (; i + 2 <= m; i += 2) {            // 2 edges per step
            int sj = __shfl(src_l, i + half);
            uint2 a = *(const uint2*)(hbase + ((size_t)sj + boff));
            acc0 += __uint_as_float(a.x << 16);
            acc1 += __uint_as_float(a.x & 0xFFFF0000u);
            acc2 += __uint_as_float(a.y << 16);
            acc3 += __uint_as_float(a.y & 0xFFFF0000u);
        }
        if (i < m) {                            // odd leftover: half 0 only
            int sj = __shfl(src_l, i);
            if (half == 0) {
                uint2 a = *(const uint2*)(hbase + ((size_t)sj + boff));
                acc0 += __uint_as_float(a.x << 16);
                acc1 += __uint_as_float(a.x & 0xFFFF0000u);
                acc2 += __uint_as_float(a.y << 16);
                acc3 += __uint_as_float(a.y & 0xFFFF0000u);
            }
        }
    }

    // combine the two halves
    acc0 += __shfl_xor(acc0, 32);
    acc1 += __shfl_xor(acc1, 32);
    acc2 += __shfl_xor(acc2, 32);
    acc3 += __shfl_xor(acc3, 32);

    if (half == 0) {
        // self-loop term (hb already prescaled by dis[node])
        uint2 a = *(const uint2*)(hbase + ((size_t)node * 256 + boff));
        acc0 += __uint_as_float(a.x << 16);
        acc1 += __uint_as_float(a.x & 0xFFFF0000u);
        acc2 += __uint_as_float(a.y << 16);
        acc3 += __uint_as_float(a.y & 0xFFFF0000u);

        float4 b4 = *(const float4*)(bias + li * 4);
        float4 r;
        r.x = fmaxf(acc0 * dc + b4.x, 0.f);
        r.y = fmaxf(acc1 * dc + b4.y, 0.f);
        r.z = fmaxf(acc2 * dc + b4.z, 0.f);
        r.w = fmaxf(acc3 * dc + b4.w, 0.f);
        *(float4*)(out + (size_t)node * D + li * 4) = r;
    }
}

extern "C" void kernel_launch(void* const* d_in, const int* in_sizes, int n_in,
                              void* d_out, int out_size, void* d_ws, size_t ws_size,
                              hipStream_t stream) {
    const float* x    = (const float*)d_in[0];
    const int*   ei   = (const int*)d_in[1];    // [2, E]: row then col
    const float* w    = (const float*)d_in[2];
    const float* bias = (const float*)d_in[3];
    float* out = (float*)d_out;

    char* ws = (char*)d_ws;
    int*      deg    = (int*)ws;              ws += N_NODES * 4;
    float*    dis    = (float*)ws;            ws += N_NODES * 4;
    int*      start  = (int*)ws;              ws += N_NODES * 4;
    int*      cur    = (int*)ws;              ws += N_NODES * 4;
    int*      btot   = (int*)ws;              ws += 256 * 4;
    __bf16*   wb     = (__bf16*)ws;           ws += D * D * 2;
    int*      srcs   = (int*)ws;              ws += (size_t)N_EDGES * 4;
    __bf16*   hb     = (__bf16*)ws;           // N_NODES * D * 2 = 25.6 MB

    const int* row = ei;
    const int* col = ei + N_EDGES;

    hipMemsetAsync(deg, 0, N_NODES * 4, stream);
    k_hist   <<<HB_BLK + 1, 1024, 0, stream>>>((const int4*)col, (const float4*)w, deg, (bf16x4*)wb);
    k_scanl  <<<NSCB, 1024, 0, stream>>>(deg, start, btot);
    k_fixup  <<<NSCB, 1024, 0, stream>>>(deg, btot, start, cur, dis);
    k_scatter<<<HB_BLK, 1024, 0, stream>>>((const int4*)row, (const int4*)col, cur, srcs);
    k_hx     <<<(N_STRIPS + 3) / 4, 256, 0, stream>>>(x, wb, dis, hb);
    k_aggregate<<<(N_NODES * 64 + 255) / 256, 256, 0, stream>>>(srcs, start, deg, hb, dis, bias, out);
}

// Round 4
// 349.356 us; speedup vs baseline: 1.0571x; 1.0571x over previous
//
#include <hip/hip_runtime.h>
#include <hip/hip_cooperative_groups.h>

namespace cg = cooperative_groups;

#define N_NODES 100000
#define N_EDGES 1600000
#define D 128
#define N_STRIPS (N_NODES / 32)     // 3125

#define BSH   9                     // coarse bucket = col >> 9 (512 nodes/bucket)
#define NBKT  196                   // ceil(100000 / 512)
#define GRID_P 256                  // cooperative grid: 1 block/CU, all co-resident
#define EPB2  (N_EDGES / GRID_P)    // 6250 edges per block, exact

typedef __bf16 bf16x4 __attribute__((ext_vector_type(4)));
typedef __bf16 bf16x8 __attribute__((ext_vector_type(8)));
typedef float  f32x4  __attribute__((ext_vector_type(4)));

// ---- fused partition: histogram -> scans -> coarse scatter -> fine sort,
// one cooperative kernel, edge slice cached in LDS across phases ----
__global__ __launch_bounds__(1024) void k_part(const int* __restrict__ row,
                                               const int* __restrict__ col,
                                               const float4* __restrict__ w4,
                                               int* __restrict__ bhist,
                                               int* __restrict__ gtot,
                                               int* __restrict__ gstart,
                                               unsigned* __restrict__ grec,
                                               int* __restrict__ srcs,
                                               int* __restrict__ deg,
                                               float* __restrict__ dis,
                                               int* __restrict__ start,
                                               bf16x4* __restrict__ wb4) {
    cg::grid_group grid = cg::this_grid();
    __shared__ int smem[13312];                 // 53 KB
    int b = blockIdx.x, tid = threadIdx.x;
    int* rowc = smem;                           // [6250]
    int* colc = smem + 6250;                    // [6250]
    int* aux  = smem + 12500;                   // [256] hist / scan / cursors

    // ---- Phase A: load+cache edge slice, coarse histogram ----
    if (tid < 256) aux[tid] = 0;
    __syncthreads();
    int e0 = b * EPB2;
    for (int i = tid; i < EPB2; i += 1024) {
        int r = row[e0 + i], c = col[e0 + i];
        rowc[i] = r; colc[i] = c;
        atomicAdd(&aux[c >> BSH], 1);
    }
    __syncthreads();
    if (tid < NBKT) bhist[tid * GRID_P + b] = aux[tid];
    grid.sync();

    // ---- Phase B: per-bucket exclusive scan over 256 block counts;
    // block NBKT casts W -> bf16 meanwhile ----
    if (b < NBKT) {
        int v = 0;
        if (tid < 256) { v = bhist[b * GRID_P + tid]; aux[tid] = v; }
        __syncthreads();
        for (int off = 1; off < 256; off <<= 1) {
            int u = 0;
            if (tid < 256 && tid >= off) u = aux[tid - off];
            __syncthreads();
            if (tid < 256) aux[tid] += u;
            __syncthreads();
        }
        if (tid < 256) bhist[b * GRID_P + tid] = aux[tid] - v;   // exclusive
        if (tid == 255) gtot[b] = aux[255];
    } else if (b == NBKT) {
        for (int i = tid; i < (D * D) / 4; i += 1024) {
            float4 u = w4[i];
            bf16x4 p;
            p[0] = (__bf16)u.x; p[1] = (__bf16)u.y;
            p[2] = (__bf16)u.z; p[3] = (__bf16)u.w;
            wb4[i] = p;
        }
    }
    grid.sync();

    // ---- Phase B2: block 0 scans bucket totals -> gstart ----
    if (b == 0) {
        int v = 0;
        if (tid < 256) { v = (tid < NBKT) ? gtot[tid] : 0; aux[tid] = v; }
        __syncthreads();
        for (int off = 1; off < 256; off <<= 1) {
            int u = 0;
            if (tid < 256 && tid >= off) u = aux[tid - off];
            __syncthreads();
            if (tid < 256) aux[tid] += u;
            __syncthreads();
        }
        if (tid < NBKT) gstart[tid] = aux[tid] - v;
    }
    grid.sync();

    // ---- Phase C: coarse scatter from LDS-cached edges ----
    if (tid < NBKT) aux[tid] = gstart[tid] + bhist[tid * GRID_P + b];
    __syncthreads();
    for (int i = tid; i < EPB2; i += 1024) {
        int c = colc[i];
        int pos = atomicAdd(&aux[c >> BSH], 1);
        grec[pos] = ((unsigned)rowc[i] << BSH) | (unsigned)(c & ((1 << BSH) - 1));
    }
    grid.sync();

    // ---- Phase D: per-bucket fine counting sort, bucket cached in LDS ----
    if (b < NBKT) {
        int cnt = gtot[b], gs = gstart[b];
        int* cache = smem;                      // [12288]
        int* fh    = smem + 12288;              // [512]
        int* fsc   = smem + 12800;              // [512]
        if (tid < 512) fh[tid] = 0;
        __syncthreads();
        for (int i = tid; i < cnt; i += 1024) {
            unsigned r = grec[gs + i];
            if (i < 12288) cache[i] = (int)r;
            atomicAdd(&fh[r & 511], 1);
        }
        __syncthreads();
        int v = 0;
        if (tid < 512) { v = fh[tid]; fsc[tid] = v; }
        __syncthreads();
        for (int off = 1; off < 512; off <<= 1) {
            int u = 0;
            if (tid < 512 && tid >= off) u = fsc[tid - off];
            __syncthreads();
            if (tid < 512) fsc[tid] += u;
            __syncthreads();
        }
        if (tid < 512) {
            int excl = fsc[tid] - v;
            int node = (b << BSH) + tid;
            if (node < N_NODES) {
                deg[node]   = v;
                dis[node]   = rsqrtf((float)v + 1.0f);
                start[node] = gs + excl;
            }
            fh[tid] = excl;                     // cursors
        }
        __syncthreads();
        for (int i = tid; i < cnt; i += 1024) {
            unsigned r = (i < 12288) ? (unsigned)cache[i] : grec[gs + i];
            int pos = atomicAdd(&fh[r & 511], 1);
            srcs[gs + pos] = (int)((r >> BSH) << 8);   // byte offset into hb
        }
    }
}

// ---- transform-first: hb[row] = bf16( (x @ W^T)[row] * dis[row] ) via bf16 MFMA ----
__global__ __launch_bounds__(256) void k_hx(const float* __restrict__ x,
                                            const __bf16* __restrict__ wb,
                                            const float* __restrict__ dis,
                                            __bf16* __restrict__ hb) {
    int wave = threadIdx.x >> 6;
    int lane = threadIdx.x & 63;
    int strip = blockIdx.x * 4 + wave;
    if (strip >= N_STRIPS) return;
    int m0 = strip * 32;
    int l15 = lane & 15;
    int kq  = lane >> 4;

    bf16x8 a[2][4];
    #pragma unroll
    for (int mt = 0; mt < 2; ++mt) {
        const float* ap = x + (size_t)(m0 + mt * 16 + l15) * D + kq * 8;
        #pragma unroll
        for (int ks = 0; ks < 4; ++ks) {
            float4 lo = *(const float4*)(ap + ks * 32);
            float4 hi = *(const float4*)(ap + ks * 32 + 4);
            bf16x8 t;
            t[0] = (__bf16)lo.x; t[1] = (__bf16)lo.y;
            t[2] = (__bf16)lo.z; t[3] = (__bf16)lo.w;
            t[4] = (__bf16)hi.x; t[5] = (__bf16)hi.y;
            t[6] = (__bf16)hi.z; t[7] = (__bf16)hi.w;
            a[mt][ks] = t;
        }
    }

    f32x4 acc[2][8] = {};
    #pragma unroll
    for (int ks = 0; ks < 4; ++ks) {
        #pragma unroll
        for (int nt = 0; nt < 8; ++nt) {
            bf16x8 b = *(const bf16x8*)(wb + (size_t)(nt * 16 + l15) * D + ks * 32 + kq * 8);
            acc[0][nt] = __builtin_amdgcn_mfma_f32_16x16x32_bf16(a[0][ks], b, acc[0][nt], 0, 0, 0);
            acc[1][nt] = __builtin_amdgcn_mfma_f32_16x16x32_bf16(a[1][ks], b, acc[1][nt], 0, 0, 0);
        }
    }

    float dsv[2][4];
    #pragma unroll
    for (int mt = 0; mt < 2; ++mt)
        #pragma unroll
        for (int r = 0; r < 4; ++r)
            dsv[mt][r] = dis[m0 + mt * 16 + kq * 4 + r];

    #pragma unroll
    for (int nt = 0; nt < 8; ++nt) {
        int colj = nt * 16 + l15;
        #pragma unroll
        for (int mt = 0; mt < 2; ++mt) {
            #pragma unroll
            for (int r = 0; r < 4; ++r) {
                int rowi = m0 + mt * 16 + kq * 4 + r;
                hb[(size_t)rowi * D + colj] = (__bf16)(acc[mt][nt][r] * dsv[mt][r]);
            }
        }
    }
}

// ---- gather-aggregate: one wave per destination, 32 lanes x 8B per row,
// two source rows per VMEM instruction; srcs hold byte offsets already ----
__global__ __launch_bounds__(256) void k_aggregate(const int* __restrict__ srcs,
                                                   const int* __restrict__ start,
                                                   const int* __restrict__ deg,
                                                   const __bf16* __restrict__ hb,
                                                   const float* __restrict__ dis,
                                                   const float* __restrict__ bias,
                                                   float* __restrict__ out) {
    int node = (blockIdx.x * 256 + threadIdx.x) >> 6;
    int lane = threadIdx.x & 63;
    if (node >= N_NODES) return;
    int li   = lane & 31;          // 8B slot within row (cols 4*li .. 4*li+3)
    int half = lane >> 5;          // which of 2 edges this half-wave handles
    int s = start[node];
    int n = deg[node];
    float dc = dis[node];
    const unsigned char* hbase = (const unsigned char*)hb;
    size_t boff = (size_t)li * 8;

    float acc0 = 0.f, acc1 = 0.f, acc2 = 0.f, acc3 = 0.f;

    for (int base = 0; base < n; base += 64) {
        int m = n - base; if (m > 64) m = 64;
        int src_l = (lane < m) ? srcs[s + base + lane] : 0;   // byte offsets
        int i = 0;
        for (; i + 16 <= m; i += 16) {          // 16 edges per batch (8 per half)
            int sv[8]; uint2 av[8];
            #pragma unroll
            for (int j = 0; j < 8; ++j)
                sv[j] = __shfl(src_l, i + 2 * j + half);
            #pragma unroll
            for (int j = 0; j < 8; ++j)
                av[j] = *(const uint2*)(hbase + ((size_t)sv[j] + boff));
            #pragma unroll
            for (int j = 0; j < 8; ++j) {
                acc0 += __uint_as_float(av[j].x << 16);
                acc1 += __uint_as_float(av[j].x & 0xFFFF0000u);
                acc2 += __uint_as_float(av[j].y << 16);
                acc3 += __uint_as_float(av[j].y & 0xFFFF0000u);
            }
        }
        for (; i + 2 <= m; i += 2) {            // 2 edges per step
            int sj = __shfl(src_l, i + half);
            uint2 a = *(const uint2*)(hbase + ((size_t)sj + boff));
            acc0 += __uint_as_float(a.x << 16);
            acc1 += __uint_as_float(a.x & 0xFFFF0000u);
            acc2 += __uint_as_float(a.y << 16);
            acc3 += __uint_as_float(a.y & 0xFFFF0000u);
        }
        if (i < m) {                            // odd leftover: half 0 only
            int sj = __shfl(src_l, i);
            if (half == 0) {
                uint2 a = *(const uint2*)(hbase + ((size_t)sj + boff));
                acc0 += __uint_as_float(a.x << 16);
                acc1 += __uint_as_float(a.x & 0xFFFF0000u);
                acc2 += __uint_as_float(a.y << 16);
                acc3 += __uint_as_float(a.y & 0xFFFF0000u);
            }
        }
    }

    // combine the two halves
    acc0 += __shfl_xor(acc0, 32);
    acc1 += __shfl_xor(acc1, 32);
    acc2 += __shfl_xor(acc2, 32);
    acc3 += __shfl_xor(acc3, 32);

    if (half == 0) {
        // self-loop term (hb already prescaled by dis[node])
        uint2 a = *(const uint2*)(hbase + ((size_t)node * 256 + boff));
        acc0 += __uint_as_float(a.x << 16);
        acc1 += __uint_as_float(a.x & 0xFFFF0000u);
        acc2 += __uint_as_float(a.y << 16);
        acc3 += __uint_as_float(a.y & 0xFFFF0000u);

        float4 b4 = *(const float4*)(bias + li * 4);
        float4 r;
        r.x = fmaxf(acc0 * dc + b4.x, 0.f);
        r.y = fmaxf(acc1 * dc + b4.y, 0.f);
        r.z = fmaxf(acc2 * dc + b4.z, 0.f);
        r.w = fmaxf(acc3 * dc + b4.w, 0.f);
        *(float4*)(out + (size_t)node * D + li * 4) = r;
    }
}

extern "C" void kernel_launch(void* const* d_in, const int* in_sizes, int n_in,
                              void* d_out, int out_size, void* d_ws, size_t ws_size,
                              hipStream_t stream) {
    const float* x    = (const float*)d_in[0];
    const int*   ei   = (const int*)d_in[1];    // [2, E]: row then col
    const float* w    = (const float*)d_in[2];
    const float* bias = (const float*)d_in[3];
    float* out = (float*)d_out;

    char* ws = (char*)d_ws;
    int*      deg    = (int*)ws;              ws += N_NODES * 4;
    float*    dis    = (float*)ws;            ws += N_NODES * 4;
    int*      start  = (int*)ws;              ws += N_NODES * 4;
    int*      bhist  = (int*)ws;              ws += NBKT * GRID_P * 4;
    int*      gtot   = (int*)ws;              ws += 256 * 4;
    int*      gstart = (int*)ws;              ws += 256 * 4;
    __bf16*   wb     = (__bf16*)ws;           ws += D * D * 2;
    unsigned* grec   = (unsigned*)ws;         ws += (size_t)N_EDGES * 4;
    int*      srcs   = (int*)ws;              ws += (size_t)N_EDGES * 4;
    __bf16*   hb     = (__bf16*)ws;           // N_NODES * D * 2 = 25.6 MB

    const int* row = ei;
    const int* col = ei + N_EDGES;
    const float4* w4 = (const float4*)w;
    bf16x4* wb4 = (bf16x4*)wb;

    void* kargs[] = {(void*)&row, (void*)&col, (void*)&w4, (void*)&bhist,
                     (void*)&gtot, (void*)&gstart, (void*)&grec, (void*)&srcs,
                     (void*)&deg, (void*)&dis, (void*)&start, (void*)&wb4};
    hipLaunchCooperativeKernel((const void*)k_part, dim3(GRID_P), dim3(1024),
                               kargs, 0, stream);
    k_hx       <<<(N_STRIPS + 3) / 4, 256, 0, stream>>>(x, wb, dis, hb);
    k_aggregate<<<(N_NODES * 64 + 255) / 256, 256, 0, stream>>>(srcs, start, deg, hb, dis, bias, out);
}

// Round 6
// 234.576 us; speedup vs baseline: 1.5744x; 1.4893x over previous
//
#include <hip/hip_runtime.h>

#define N_NODES 100000
#define N_EDGES 1600000
#define D 128
#define N_STRIPS (N_NODES / 32)     // 3125

#define BSH   9                     // coarse bucket = col >> 9 (512 nodes/bucket)
#define NBKT  196                   // ceil(100000 / 512)
#define P_BLK 160                   // partition blocks; EPB = 10000 exactly
#define EPB   (N_EDGES / P_BLK)
#define SL_CAP 6144                 // per-slice record cap (avg ~2041)

typedef __bf16 bf16x4 __attribute__((ext_vector_type(4)));
typedef __bf16 bf16x8 __attribute__((ext_vector_type(8)));
typedef float  f32x4  __attribute__((ext_vector_type(4)));

// ---- P1 fused: blocks 0..P_BLK-1 build coarse histogram; block P_BLK casts W ----
__global__ __launch_bounds__(1024) void k_prep(const int* __restrict__ col,
                                               const float4* __restrict__ w4,
                                               int* __restrict__ bhist,
                                               bf16x4* __restrict__ wb4) {
    int tid = threadIdx.x, b = blockIdx.x;
    if (b == P_BLK) {                      // cast W -> bf16 (4096 float4)
        for (int i = tid; i < (D * D) / 4; i += 1024) {
            float4 u = w4[i];
            bf16x4 p;
            p[0] = (__bf16)u.x; p[1] = (__bf16)u.y;
            p[2] = (__bf16)u.z; p[3] = (__bf16)u.w;
            wb4[i] = p;
        }
        return;
    }
    __shared__ int lh[NBKT];
    if (tid < NBKT) lh[tid] = 0;
    __syncthreads();
    int e0 = b * EPB;
    for (int e = e0 + tid; e < e0 + EPB; e += 1024)
        atomicAdd(&lh[col[e] >> BSH], 1);
    __syncthreads();
    if (tid < NBKT) bhist[tid * P_BLK + b] = lh[tid];
}

// ---- P2a: per-bucket exclusive scan over the 160 block counts (in place) ----
__global__ __launch_bounds__(256) void k_bscan(int* __restrict__ bhist,
                                               int* __restrict__ gtot) {
    __shared__ int buf[256];
    int k = blockIdx.x, t = threadIdx.x;
    int v = (t < P_BLK) ? bhist[k * P_BLK + t] : 0;
    buf[t] = v;
    __syncthreads();
    for (int off = 1; off < 256; off <<= 1) {
        int u = (t >= off) ? buf[t - off] : 0;
        __syncthreads();
        buf[t] += u;
        __syncthreads();
    }
    if (t < P_BLK) bhist[k * P_BLK + t] = buf[t] - v;   // exclusive
    if (t == 255) gtot[k] = buf[255];
}

// ---- P2b: exclusive scan of bucket totals -> gstart ----
__global__ __launch_bounds__(256) void k_gscan(const int* __restrict__ gtot,
                                               int* __restrict__ gstart) {
    __shared__ int buf[256];
    int t = threadIdx.x;
    int v = (t < NBKT) ? gtot[t] : 0;
    buf[t] = v;
    __syncthreads();
    for (int off = 1; off < 256; off <<= 1) {
        int u = (t >= off) ? buf[t - off] : 0;
        __syncthreads();
        buf[t] += u;
        __syncthreads();
    }
    if (t < NBKT) gstart[t] = buf[t] - v;
}

// ---- P3: direct scatter; per-block LDS cursors, zero global atomics ----
__global__ __launch_bounds__(1024) void k_cscatter(const int* __restrict__ row,
                                                   const int* __restrict__ col,
                                                   const int* __restrict__ bhist,
                                                   const int* __restrict__ gstart,
                                                   unsigned* __restrict__ grec) {
    __shared__ int cur[NBKT];
    int b = blockIdx.x, t = threadIdx.x;
    if (t < NBKT) cur[t] = gstart[t] + bhist[t * P_BLK + b];
    __syncthreads();
    int e0 = b * EPB;
    for (int e = e0 + t; e < e0 + EPB; e += 1024) {
        int c = col[e];
        unsigned rec = ((unsigned)row[e] << BSH) | (unsigned)(c & ((1 << BSH) - 1));
        int pos = atomicAdd(&cur[c >> BSH], 1);
        grec[pos] = rec;
    }
}

// ---- P4 (shrunk): per-bucket count + scan only -> deg/dis/start ----
__global__ __launch_bounds__(1024) void k_fine2(const unsigned* __restrict__ grec,
                                                const int* __restrict__ gtot,
                                                const int* __restrict__ gstart,
                                                int* __restrict__ deg,
                                                float* __restrict__ dis,
                                                int* __restrict__ start) {
    __shared__ int fh[512];
    __shared__ int fsc[512];
    int b = blockIdx.x;
    int tid = threadIdx.x;
    int cnt = gtot[b];
    int gs = gstart[b];
    if (tid < 512) fh[tid] = 0;
    __syncthreads();
    for (int i = tid; i < cnt; i += 1024)
        atomicAdd(&fh[grec[gs + i] & 511], 1);
    __syncthreads();
    int v = 0;
    if (tid < 512) { v = fh[tid]; fsc[tid] = v; }
    __syncthreads();
    for (int off = 1; off < 512; off <<= 1) {
        int u = 0;
        if (tid < 512 && tid >= off) u = fsc[tid - off];
        __syncthreads();
        if (tid < 512) fsc[tid] += u;
        __syncthreads();
    }
    if (tid < 512) {
        int node = (b << BSH) + tid;
        if (node < N_NODES) {
            deg[node]   = v;
            dis[node]   = rsqrtf((float)v + 1.0f);
            start[node] = gs + fsc[tid] - v;    // global exclusive position
        }
    }
}

// ---- transform-first: hb[row] = bf16( (x @ W^T)[row] * dis[row] ) via bf16 MFMA ----
__global__ __launch_bounds__(256) void k_hx(const float* __restrict__ x,
                                            const __bf16* __restrict__ wb,
                                            const float* __restrict__ dis,
                                            __bf16* __restrict__ hb) {
    int wave = threadIdx.x >> 6;
    int lane = threadIdx.x & 63;
    int strip = blockIdx.x * 4 + wave;
    if (strip >= N_STRIPS) return;
    int m0 = strip * 32;
    int l15 = lane & 15;
    int kq  = lane >> 4;

    bf16x8 a[2][4];
    #pragma unroll
    for (int mt = 0; mt < 2; ++mt) {
        const float* ap = x + (size_t)(m0 + mt * 16 + l15) * D + kq * 8;
        #pragma unroll
        for (int ks = 0; ks < 4; ++ks) {
            float4 lo = *(const float4*)(ap + ks * 32);
            float4 hi = *(const float4*)(ap + ks * 32 + 4);
            bf16x8 t;
            t[0] = (__bf16)lo.x; t[1] = (__bf16)lo.y;
            t[2] = (__bf16)lo.z; t[3] = (__bf16)lo.w;
            t[4] = (__bf16)hi.x; t[5] = (__bf16)hi.y;
            t[6] = (__bf16)hi.z; t[7] = (__bf16)hi.w;
            a[mt][ks] = t;
        }
    }

    f32x4 acc[2][8] = {};
    #pragma unroll
    for (int ks = 0; ks < 4; ++ks) {
        #pragma unroll
        for (int nt = 0; nt < 8; ++nt) {
            bf16x8 b = *(const bf16x8*)(wb + (size_t)(nt * 16 + l15) * D + ks * 32 + kq * 8);
            acc[0][nt] = __builtin_amdgcn_mfma_f32_16x16x32_bf16(a[0][ks], b, acc[0][nt], 0, 0, 0);
            acc[1][nt] = __builtin_amdgcn_mfma_f32_16x16x32_bf16(a[1][ks], b, acc[1][nt], 0, 0, 0);
        }
    }

    float dsv[2][4];
    #pragma unroll
    for (int mt = 0; mt < 2; ++mt)
        #pragma unroll
        for (int r = 0; r < 4; ++r)
            dsv[mt][r] = dis[m0 + mt * 16 + kq * 4 + r];

    #pragma unroll
    for (int nt = 0; nt < 8; ++nt) {
        int colj = nt * 16 + l15;
        #pragma unroll
        for (int mt = 0; mt < 2; ++mt) {
            #pragma unroll
            for (int r = 0; r < 4; ++r) {
                int rowi = m0 + mt * 16 + kq * 4 + r;
                hb[(size_t)rowi * D + colj] = (__bf16)(acc[mt][nt][r] * dsv[mt][r]);
            }
        }
    }
}

// ---- fused fine-place + gather-aggregate: one block per 128-node slice of a
// bucket; replay bucket records, place slice's srcs (pre-shifted byte offsets)
// into LDS, then the verified gather inner loop with LDS srcs ----
__global__ __launch_bounds__(512) void k_aggregate(const unsigned* __restrict__ grec,
                                                   const int* __restrict__ gtot,
                                                   const int* __restrict__ gstart,
                                                   const int* __restrict__ start,
                                                   const int* __restrict__ deg,
                                                   const __bf16* __restrict__ hb,
                                                   const float* __restrict__ dis,
                                                   const float* __restrict__ bias,
                                                   float* __restrict__ out) {
    __shared__ int srcsL[SL_CAP];
    __shared__ int cur[128];
    __shared__ int sbase_s;
    int blk = blockIdx.x;
    int b  = blk >> 2;
    int sl = blk & 3;
    int cnt = gtot[b];
    int gs  = gstart[b];
    int node0 = (b << BSH) + sl * 128;
    int t = threadIdx.x;

    if (t == 0)
        sbase_s = (node0 < N_NODES) ? start[node0] : gs + cnt;
    if (t < 128) {
        int nd = node0 + t;
        cur[t] = (nd < N_NODES) ? start[nd] : gs + cnt;
    }
    __syncthreads();
    int sbase = sbase_s;
    if (t < 128) cur[t] -= sbase;
    __syncthreads();

    int lo = sl * 128;
    for (int i = t; i < cnt; i += 512) {
        unsigned r = grec[gs + i];
        int s = (int)(r & 511) - lo;
        if ((unsigned)s < 128u) {
            int p = atomicAdd(&cur[s], 1);
            if (p < SL_CAP) srcsL[p] = (int)((r >> BSH) << 8);   // byte offset into hb
        }
    }
    __syncthreads();

    int wave = t >> 6;
    int lane = t & 63;
    int li   = lane & 31;          // 8B slot within row
    int half = lane >> 5;          // which of 2 edges this half-wave handles
    const unsigned char* hbase = (const unsigned char*)hb;
    size_t boff = (size_t)li * 8;

    for (int k = 0; k < 16; ++k) {
        int nd = node0 + wave * 16 + k;
        if (nd >= N_NODES) break;
        int n  = deg[nd];
        int s0 = start[nd] - sbase;
        float dc = dis[nd];

        float acc0 = 0.f, acc1 = 0.f, acc2 = 0.f, acc3 = 0.f;

        for (int base = 0; base < n; base += 64) {
            int m = n - base; if (m > 64) m = 64;
            int src_l = (lane < m) ? srcsL[s0 + base + lane] : 0;   // byte offsets
            int i = 0;
            for (; i + 16 <= m; i += 16) {          // 16 edges per batch (8 per half)
                int sv[8]; uint2 av[8];
                #pragma unroll
                for (int j = 0; j < 8; ++j)
                    sv[j] = __shfl(src_l, i + 2 * j + half);
                #pragma unroll
                for (int j = 0; j < 8; ++j)
                    av[j] = *(const uint2*)(hbase + ((size_t)sv[j] + boff));
                #pragma unroll
                for (int j = 0; j < 8; ++j) {
                    acc0 += __uint_as_float(av[j].x << 16);
                    acc1 += __uint_as_float(av[j].x & 0xFFFF0000u);
                    acc2 += __uint_as_float(av[j].y << 16);
                    acc3 += __uint_as_float(av[j].y & 0xFFFF0000u);
                }
            }
            for (; i + 2 <= m; i += 2) {            // 2 edges per step
                int sj = __shfl(src_l, i + half);
                uint2 a = *(const uint2*)(hbase + ((size_t)sj + boff));
                acc0 += __uint_as_float(a.x << 16);
                acc1 += __uint_as_float(a.x & 0xFFFF0000u);
                acc2 += __uint_as_float(a.y << 16);
                acc3 += __uint_as_float(a.y & 0xFFFF0000u);
            }
            if (i < m) {                            // odd leftover: half 0 only
                int sj = __shfl(src_l, i);
                if (half == 0) {
                    uint2 a = *(const uint2*)(hbase + ((size_t)sj + boff));
                    acc0 += __uint_as_float(a.x << 16);
                    acc1 += __uint_as_float(a.x & 0xFFFF0000u);
                    acc2 += __uint_as_float(a.y << 16);
                    acc3 += __uint_as_float(a.y & 0xFFFF0000u);
                }
            }
        }

        // combine the two halves
        acc0 += __shfl_xor(acc0, 32);
        acc1 += __shfl_xor(acc1, 32);
        acc2 += __shfl_xor(acc2, 32);
        acc3 += __shfl_xor(acc3, 32);

        if (half == 0) {
            // self-loop term (hb already prescaled by dis[node])
            uint2 a = *(const uint2*)(hbase + ((size_t)nd * 256 + boff));
            acc0 += __uint_as_float(a.x << 16);
            acc1 += __uint_as_float(a.x & 0xFFFF0000u);
            acc2 += __uint_as_float(a.y << 16);
            acc3 += __uint_as_float(a.y & 0xFFFF0000u);

            float4 b4 = *(const float4*)(bias + li * 4);
            float4 r;
            r.x = fmaxf(acc0 * dc + b4.x, 0.f);
            r.y = fmaxf(acc1 * dc + b4.y, 0.f);
            r.z = fmaxf(acc2 * dc + b4.z, 0.f);
            r.w = fmaxf(acc3 * dc + b4.w, 0.f);
            *(float4*)(out + (size_t)nd * D + li * 4) = r;
        }
    }
}

extern "C" void kernel_launch(void* const* d_in, const int* in_sizes, int n_in,
                              void* d_out, int out_size, void* d_ws, size_t ws_size,
                              hipStream_t stream) {
    const float* x    = (const float*)d_in[0];
    const int*   ei   = (const int*)d_in[1];    // [2, E]: row then col
    const float* w    = (const float*)d_in[2];
    const float* bias = (const float*)d_in[3];
    float* out = (float*)d_out;

    char* ws = (char*)d_ws;
    int*      deg    = (int*)ws;              ws += N_NODES * 4;
    float*    dis    = (float*)ws;            ws += N_NODES * 4;
    int*      start  = (int*)ws;              ws += N_NODES * 4;
    int*      bhist  = (int*)ws;              ws += NBKT * P_BLK * 4;
    int*      gtot   = (int*)ws;              ws += 256 * 4;
    int*      gstart = (int*)ws;              ws += 256 * 4;
    __bf16*   wb     = (__bf16*)ws;           ws += D * D * 2;
    unsigned* grec   = (unsigned*)ws;         ws += (size_t)N_EDGES * 4;
    __bf16*   hb     = (__bf16*)ws;           // N_NODES * D * 2 = 25.6 MB

    const int* row = ei;
    const int* col = ei + N_EDGES;

    k_prep     <<<P_BLK + 1, 1024, 0, stream>>>(col, (const float4*)w, bhist, (bf16x4*)wb);
    k_bscan    <<<NBKT, 256, 0, stream>>>(bhist, gtot);
    k_gscan    <<<1, 256, 0, stream>>>(gtot, gstart);
    k_cscatter <<<P_BLK, 1024, 0, stream>>>(row, col, bhist, gstart, grec);
    k_fine2    <<<NBKT, 1024, 0, stream>>>(grec, gtot, gstart, deg, dis, start);
    k_hx       <<<(N_STRIPS + 3) / 4, 256, 0, stream>>>(x, wb, dis, hb);
    k_aggregate<<<NBKT * 4, 512, 0, stream>>>(grec, gtot, gstart, start, deg, hb, dis, bias, out);
}

// Round 7
// 227.717 us; speedup vs baseline: 1.6218x; 1.0301x over previous
//
#include <hip/hip_runtime.h>

#define N_NODES 100000
#define N_EDGES 1600000
#define D 128
#define N_STRIPS (N_NODES / 32)     // 3125

#define BSH   8                     // coarse bucket = col >> 8 (256 nodes/bucket)
#define NBKT  391                   // ceil(100000 / 256)
#define P_BLK 512                   // partition blocks; EPB = 3125 exactly
#define EPB   (N_EDGES / P_BLK)

typedef __bf16 bf16x4 __attribute__((ext_vector_type(4)));
typedef __bf16 bf16x8 __attribute__((ext_vector_type(8)));
typedef float  f32x4  __attribute__((ext_vector_type(4)));

// ---- P1 fused: blocks 0..P_BLK-1 build coarse histogram; block P_BLK casts W ----
__global__ __launch_bounds__(1024) void k_prep(const int* __restrict__ col,
                                               const float4* __restrict__ w4,
                                               int* __restrict__ bhist,
                                               bf16x4* __restrict__ wb4) {
    int tid = threadIdx.x, b = blockIdx.x;
    if (b == P_BLK) {                      // cast W -> bf16 (4096 float4)
        for (int i = tid; i < (D * D) / 4; i += 1024) {
            float4 u = w4[i];
            bf16x4 p;
            p[0] = (__bf16)u.x; p[1] = (__bf16)u.y;
            p[2] = (__bf16)u.z; p[3] = (__bf16)u.w;
            wb4[i] = p;
        }
        return;
    }
    __shared__ int lh[NBKT];
    if (tid < NBKT) lh[tid] = 0;
    __syncthreads();
    int e0 = b * EPB;
    for (int e = e0 + tid; e < e0 + EPB; e += 1024)
        atomicAdd(&lh[col[e] >> BSH], 1);
    __syncthreads();
    if (tid < NBKT) bhist[tid * P_BLK + b] = lh[tid];
}

// ---- P2a: per-bucket exclusive scan over the 512 block counts (in place) ----
__global__ __launch_bounds__(512) void k_bscan(int* __restrict__ bhist,
                                               int* __restrict__ gtot) {
    __shared__ int buf[512];
    int k = blockIdx.x, t = threadIdx.x;
    int v = bhist[k * P_BLK + t];
    buf[t] = v;
    __syncthreads();
    for (int off = 1; off < 512; off <<= 1) {
        int u = (t >= off) ? buf[t - off] : 0;
        __syncthreads();
        buf[t] += u;
        __syncthreads();
    }
    bhist[k * P_BLK + t] = buf[t] - v;   // exclusive
    if (t == 511) gtot[k] = buf[511];
}

// ---- P2b: exclusive scan of bucket totals -> gstart ----
__global__ __launch_bounds__(512) void k_gscan(const int* __restrict__ gtot,
                                               int* __restrict__ gstart) {
    __shared__ int buf[512];
    int t = threadIdx.x;
    int v = (t < NBKT) ? gtot[t] : 0;
    buf[t] = v;
    __syncthreads();
    for (int off = 1; off < 512; off <<= 1) {
        int u = (t >= off) ? buf[t - off] : 0;
        __syncthreads();
        buf[t] += u;
        __syncthreads();
    }
    if (t < NBKT) gstart[t] = buf[t] - v;
}

// ---- P3: direct scatter; per-block LDS cursors, zero global atomics ----
__global__ __launch_bounds__(1024) void k_cscatter(const int* __restrict__ row,
                                                   const int* __restrict__ col,
                                                   const int* __restrict__ bhist,
                                                   const int* __restrict__ gstart,
                                                   unsigned* __restrict__ grec) {
    __shared__ int cur[NBKT];
    int b = blockIdx.x, t = threadIdx.x;
    if (t < NBKT) cur[t] = gstart[t] + bhist[t * P_BLK + b];
    __syncthreads();
    int e0 = b * EPB;
    for (int e = e0 + t; e < e0 + EPB; e += 1024) {
        int c = col[e];
        unsigned rec = ((unsigned)row[e] << BSH) | (unsigned)(c & ((1 << BSH) - 1));
        int pos = atomicAdd(&cur[c >> BSH], 1);
        grec[pos] = rec;
    }
}

// ---- P4: per-bucket fine sort (256 nodes/bucket); emits deg/dis/start and
// srcs as pre-shifted byte offsets into hb ----
__global__ __launch_bounds__(1024) void k_fine(const unsigned* __restrict__ grec,
                                               const int* __restrict__ gtot,
                                               const int* __restrict__ gstart,
                                               int* __restrict__ deg,
                                               float* __restrict__ dis,
                                               int* __restrict__ start,
                                               int* __restrict__ srcs) {
    __shared__ int fh[256];
    __shared__ int fsc[256];
    int b = blockIdx.x;
    int tid = threadIdx.x;
    int cnt = gtot[b];
    int gs = gstart[b];
    if (tid < 256) fh[tid] = 0;
    __syncthreads();
    for (int i = tid; i < cnt; i += 1024)
        atomicAdd(&fh[grec[gs + i] & 255], 1);
    __syncthreads();
    int v = 0;
    if (tid < 256) { v = fh[tid]; fsc[tid] = v; }
    __syncthreads();
    for (int off = 1; off < 256; off <<= 1) {
        int u = 0;
        if (tid < 256 && tid >= off) u = fsc[tid - off];
        __syncthreads();
        if (tid < 256) fsc[tid] += u;
        __syncthreads();
    }
    if (tid < 256) {
        int excl = fsc[tid] - v;              // exclusive scan value
        int node = (b << BSH) + tid;
        if (node < N_NODES) {
            deg[node]   = v;
            dis[node]   = rsqrtf((float)v + 1.0f);
            start[node] = gs + excl;
        }
        fh[tid] = excl;                       // -> cursors
    }
    __syncthreads();
    for (int i = tid; i < cnt; i += 1024) {
        unsigned r = grec[gs + i];
        int pos = atomicAdd(&fh[r & 255], 1);
        srcs[gs + pos] = (int)((r >> BSH) << 8);   // row * 256 = byte offset into hb
    }
}

// ---- transform-first: hb[row] = bf16( (x @ W^T)[row] * dis[row] ) via bf16 MFMA ----
__global__ __launch_bounds__(256) void k_hx(const float* __restrict__ x,
                                            const __bf16* __restrict__ wb,
                                            const float* __restrict__ dis,
                                            __bf16* __restrict__ hb) {
    int wave = threadIdx.x >> 6;
    int lane = threadIdx.x & 63;
    int strip = blockIdx.x * 4 + wave;
    if (strip >= N_STRIPS) return;
    int m0 = strip * 32;
    int l15 = lane & 15;
    int kq  = lane >> 4;

    bf16x8 a[2][4];
    #pragma unroll
    for (int mt = 0; mt < 2; ++mt) {
        const float* ap = x + (size_t)(m0 + mt * 16 + l15) * D + kq * 8;
        #pragma unroll
        for (int ks = 0; ks < 4; ++ks) {
            float4 lo = *(const float4*)(ap + ks * 32);
            float4 hi = *(const float4*)(ap + ks * 32 + 4);
            bf16x8 t;
            t[0] = (__bf16)lo.x; t[1] = (__bf16)lo.y;
            t[2] = (__bf16)lo.z; t[3] = (__bf16)lo.w;
            t[4] = (__bf16)hi.x; t[5] = (__bf16)hi.y;
            t[6] = (__bf16)hi.z; t[7] = (__bf16)hi.w;
            a[mt][ks] = t;
        }
    }

    f32x4 acc[2][8] = {};
    #pragma unroll
    for (int ks = 0; ks < 4; ++ks) {
        #pragma unroll
        for (int nt = 0; nt < 8; ++nt) {
            bf16x8 b = *(const bf16x8*)(wb + (size_t)(nt * 16 + l15) * D + ks * 32 + kq * 8);
            acc[0][nt] = __builtin_amdgcn_mfma_f32_16x16x32_bf16(a[0][ks], b, acc[0][nt], 0, 0, 0);
            acc[1][nt] = __builtin_amdgcn_mfma_f32_16x16x32_bf16(a[1][ks], b, acc[1][nt], 0, 0, 0);
        }
    }

    float dsv[2][4];
    #pragma unroll
    for (int mt = 0; mt < 2; ++mt)
        #pragma unroll
        for (int r = 0; r < 4; ++r)
            dsv[mt][r] = dis[m0 + mt * 16 + kq * 4 + r];

    #pragma unroll
    for (int nt = 0; nt < 8; ++nt) {
        int colj = nt * 16 + l15;
        #pragma unroll
        for (int mt = 0; mt < 2; ++mt) {
            #pragma unroll
            for (int r = 0; r < 4; ++r) {
                int rowi = m0 + mt * 16 + kq * 4 + r;
                hb[(size_t)rowi * D + colj] = (__bf16)(acc[mt][nt][r] * dsv[mt][r]);
            }
        }
    }
}

// ---- gather-aggregate: one wave per destination, 32 lanes x 8B per row,
// two source rows per VMEM instruction; srcs hold byte offsets already ----
__global__ __launch_bounds__(256) void k_aggregate(const int* __restrict__ srcs,
                                                   const int* __restrict__ start,
                                                   const int* __restrict__ deg,
                                                   const __bf16* __restrict__ hb,
                                                   const float* __restrict__ dis,
                                                   const float* __restrict__ bias,
                                                   float* __restrict__ out) {
    int node = (blockIdx.x * 256 + threadIdx.x) >> 6;
    int lane = threadIdx.x & 63;
    if (node >= N_NODES) return;
    int li   = lane & 31;          // 8B slot within row (cols 4*li .. 4*li+3)
    int half = lane >> 5;          // which of 2 edges this half-wave handles
    int s = start[node];
    int n = deg[node];
    float dc = dis[node];
    const unsigned char* hbase = (const unsigned char*)hb;
    size_t boff = (size_t)li * 8;

    float acc0 = 0.f, acc1 = 0.f, acc2 = 0.f, acc3 = 0.f;

    for (int base = 0; base < n; base += 64) {
        int m = n - base; if (m > 64) m = 64;
        int src_l = (lane < m) ? srcs[s + base + lane] : 0;   // byte offsets
        int i = 0;
        for (; i + 16 <= m; i += 16) {          // 16 edges per batch (8 per half)
            int sv[8]; uint2 av[8];
            #pragma unroll
            for (int j = 0; j < 8; ++j)
                sv[j] = __shfl(src_l, i + 2 * j + half);
            #pragma unroll
            for (int j = 0; j < 8; ++j)
                av[j] = *(const uint2*)(hbase + ((size_t)sv[j] + boff));
            #pragma unroll
            for (int j = 0; j < 8; ++j) {
                acc0 += __uint_as_float(av[j].x << 16);
                acc1 += __uint_as_float(av[j].x & 0xFFFF0000u);
                acc2 += __uint_as_float(av[j].y << 16);
                acc3 += __uint_as_float(av[j].y & 0xFFFF0000u);
            }
        }
        for (; i + 2 <= m; i += 2) {            // 2 edges per step
            int sj = __shfl(src_l, i + half);
            uint2 a = *(const uint2*)(hbase + ((size_t)sj + boff));
            acc0 += __uint_as_float(a.x << 16);
            acc1 += __uint_as_float(a.x & 0xFFFF0000u);
            acc2 += __uint_as_float(a.y << 16);
            acc3 += __uint_as_float(a.y & 0xFFFF0000u);
        }
        if (i < m) {                            // odd leftover: half 0 only
            int sj = __shfl(src_l, i);
            if (half == 0) {
                uint2 a = *(const uint2*)(hbase + ((size_t)sj + boff));
                acc0 += __uint_as_float(a.x << 16);
                acc1 += __uint_as_float(a.x & 0xFFFF0000u);
                acc2 += __uint_as_float(a.y << 16);
                acc3 += __uint_as_float(a.y & 0xFFFF0000u);
            }
        }
    }

    // combine the two halves
    acc0 += __shfl_xor(acc0, 32);
    acc1 += __shfl_xor(acc1, 32);
    acc2 += __shfl_xor(acc2, 32);
    acc3 += __shfl_xor(acc3, 32);

    if (half == 0) {
        // self-loop term (hb already prescaled by dis[node])
        uint2 a = *(const uint2*)(hbase + ((size_t)node * 256 + boff));
        acc0 += __uint_as_float(a.x << 16);
        acc1 += __uint_as_float(a.x & 0xFFFF0000u);
        acc2 += __uint_as_float(a.y << 16);
        acc3 += __uint_as_float(a.y & 0xFFFF0000u);

        float4 b4 = *(const float4*)(bias + li * 4);
        float4 r;
        r.x = fmaxf(acc0 * dc + b4.x, 0.f);
        r.y = fmaxf(acc1 * dc + b4.y, 0.f);
        r.z = fmaxf(acc2 * dc + b4.z, 0.f);
        r.w = fmaxf(acc3 * dc + b4.w, 0.f);
        *(float4*)(out + (size_t)node * D + li * 4) = r;
    }
}

extern "C" void kernel_launch(void* const* d_in, const int* in_sizes, int n_in,
                              void* d_out, int out_size, void* d_ws, size_t ws_size,
                              hipStream_t stream) {
    const float* x    = (const float*)d_in[0];
    const int*   ei   = (const int*)d_in[1];    // [2, E]: row then col
    const float* w    = (const float*)d_in[2];
    const float* bias = (const float*)d_in[3];
    float* out = (float*)d_out;

    char* ws = (char*)d_ws;
    int*      deg    = (int*)ws;              ws += N_NODES * 4;
    float*    dis    = (float*)ws;            ws += N_NODES * 4;
    int*      start  = (int*)ws;              ws += N_NODES * 4;
    int*      bhist  = (int*)ws;              ws += (size_t)NBKT * P_BLK * 4;
    int*      gtot   = (int*)ws;              ws += 512 * 4;
    int*      gstart = (int*)ws;              ws += 512 * 4;
    __bf16*   wb     = (__bf16*)ws;           ws += D * D * 2;
    unsigned* grec   = (unsigned*)ws;         ws += (size_t)N_EDGES * 4;
    int*      srcs   = (int*)ws;              ws += (size_t)N_EDGES * 4;
    __bf16*   hb     = (__bf16*)ws;           // N_NODES * D * 2 = 25.6 MB

    const int* row = ei;
    const int* col = ei + N_EDGES;

    k_prep     <<<P_BLK + 1, 1024, 0, stream>>>(col, (const float4*)w, bhist, (bf16x4*)wb);
    k_bscan    <<<NBKT, 512, 0, stream>>>(bhist, gtot);
    k_gscan    <<<1, 512, 0, stream>>>(gtot, gstart);
    k_cscatter <<<P_BLK, 1024, 0, stream>>>(row, col, bhist, gstart, grec);
    k_fine     <<<NBKT, 1024, 0, stream>>>(grec, gtot, gstart, deg, dis, start, srcs);
    k_hx       <<<(N_STRIPS + 3) / 4, 256, 0, stream>>>(x, wb, dis, hb);
    k_aggregate<<<(N_NODES * 64 + 255) / 256, 256, 0, stream>>>(srcs, start, deg, hb, dis, bias, out);
}